// Round 5
// baseline (657.769 us; speedup 1.0000x reference)
//
#include <hip/hip_runtime.h>
#include <stdint.h>

// Problem constants (from reference)
constexpr int BATCH  = 5;
constexpr int DIN    = 20;
constexpr int DHID   = 60;
constexpr int NNODES = 204800;
constexpr int NUW    = 12;   // unary width
constexpr int NBW    = 4;    // binary width
constexpr int TOT    = NNODES / 2 * NUW + NNODES / 2 * NBW;  // 1,638,400
constexpr int NPB    = 32;                 // nodes per block (main kernel)
constexpr int NBLK   = NNODES / NPB;       // 6400
constexpr int TPB    = 256;
constexpr long long PROBS_ELEMS = (long long)BATCH * NNODES * 12;  // 12,288,000
constexpr double TINYF = 1.1754943508222875e-38;   // np.finfo(float32).tiny
constexpr double INV23 = 1.1920928955078125e-7;    // 2^-23

// ---------------- threefry2x32, key = threefry_seed(1) = (0, 1) ----------------
__device__ __forceinline__ uint32_t rotl32(uint32_t x, int r) {
  return (x << r) | (x >> (32 - r));
}

__device__ __forceinline__ void tf2x32(uint32_t x0, uint32_t x1,
                                       uint32_t &o0, uint32_t &o1) {
  const uint32_t ks0 = 0u, ks1 = 1u, ks2 = 0x1BD11BDBu;  // 0^1^0x1BD11BDA
  x0 += ks0; x1 += ks1;
#define TF_R(r) { x0 += x1; x1 = rotl32(x1, (r)); x1 ^= x0; }
  TF_R(13) TF_R(15) TF_R(26) TF_R(6)
  x0 += ks1; x1 += ks2 + 1u;
  TF_R(17) TF_R(29) TF_R(16) TF_R(24)
  x0 += ks2; x1 += ks0 + 2u;
  TF_R(13) TF_R(15) TF_R(26) TF_R(6)
  x0 += ks0; x1 += ks1 + 3u;
  TF_R(17) TF_R(29) TF_R(16) TF_R(24)
  x0 += ks1; x1 += ks2 + 4u;
  TF_R(13) TF_R(15) TF_R(26) TF_R(6)
  x0 += ks2; x1 += ks0 + 5u;
#undef TF_R
  o0 = x0; o1 = x1;
}

// jax_threefry_partitionable=True semantics: counter is 64-bit iota over the
// flat (5,204800,12) array; for i < 2^32: x0 = 0, x1 = i; bits = out0 ^ out1.
__device__ __forceinline__ double gumbel_at(uint32_t i) {
  uint32_t o0, o1;
  tf2x32(0u, i, o0, o1);
  uint32_t bits = o0 ^ o1;
  uint32_t mant = bits >> 9;                       // 23 random mantissa bits
  double f = (double)mant * INV23;                 // uniform in [0,1)
  double u = f * (1.0 - TINYF) + TINYF;            // np/jax uniform(minval=tiny, maxval=1)
  u = fmax(TINYF, u);
  return -log(-log(u));
}

// ---------------- Kernel A: width sums per 32-node group ----------------
__global__ void kA(const int* __restrict__ nis, int* __restrict__ gs) {
  __shared__ int w[1024];
  int base = blockIdx.x * 1024;
  for (int r = 0; r < 4; ++r) {
    int idx = base + r * 256 + threadIdx.x;
    w[r * 256 + threadIdx.x] = (nis[idx] == 1) ? NUW : NBW;
  }
  __syncthreads();
  if (threadIdx.x < 32) {
    int s = 0;
    for (int q = 0; q < 32; ++q) s += w[threadIdx.x * 32 + q];
    gs[blockIdx.x * 32 + threadIdx.x] = s;
  }
}

// ---------------- Kernel B: exclusive scan of 6400 group sums + hidden (f64) ----------------
__global__ void kB(const int* __restrict__ gs, int* __restrict__ gstart,
                   const float* __restrict__ x, const float* __restrict__ W1,
                   const float* __restrict__ b1, double* __restrict__ hid) {
  __shared__ int sc[1024];
  int tid = threadIdx.x;
  int s0 = tid * 7;
  int e0 = min(s0 + 7, NBLK);
  int part = 0;
  for (int e = s0; e < e0; ++e) part += gs[e];
  sc[tid] = part;
  __syncthreads();
  for (int d = 1; d < 1024; d <<= 1) {
    int v = (tid >= d) ? sc[tid - d] : 0;
    __syncthreads();
    sc[tid] += v;
    __syncthreads();
  }
  int run = sc[tid] - part;  // exclusive prefix of this thread's chunk
  for (int e = s0; e < e0; ++e) { gstart[e] = run; run += gs[e]; }

  // hidden[h*5+b] = relu(x[b,:] @ W1[:,h] + b1[h]) in f64
  if (tid < BATCH * DHID) {
    int b = tid / DHID, h = tid % DHID;
    double acc = (double)b1[h];
    for (int k = 0; k < DIN; ++k)
      acc += (double)x[b * DIN + k] * (double)W1[k * DHID + h];
    hid[h * BATCH + b] = acc > 0.0 ? acc : 0.0;
  }
}

// ---------------- Kernel C: main ----------------
__global__ __launch_bounds__(TPB) void kC(
    const float* __restrict__ W2, const float* __restrict__ b2,
    const int* __restrict__ nis, const double* __restrict__ hid,
    const int* __restrict__ gstart, float* __restrict__ out) {
  __shared__ double sh_hid[DHID * BATCH];                 // [k*5+b], 2400 B
  __shared__ double lg[BATCH][NPB * 12];                  // logits (tanh'd), packed, 15360 B
  __shared__ __align__(16) float pbuf[BATCH][NPB * 12];   // probs staging, 7680 B
  __shared__ int lco[NPB + 1];
  __shared__ int nw[NPB];

  int tid = threadIdx.x;
  int g = blockIdx.x;
  int n0 = g * NPB;

  // FIX: DHID*BATCH = 300 > TPB = 256 — must stride, or sh_hid[256..299] is garbage.
  for (int tpos = tid; tpos < DHID * BATCH; tpos += TPB) sh_hid[tpos] = hid[tpos];
  if (tid == 0) {
    int run = 0;
    for (int i = 0; i < NPB; ++i) {
      int wd = (nis[n0 + i] == 1) ? NUW : NBW;
      nw[i] = wd; lco[i] = run; run += wd;
    }
    lco[NPB] = run;
  }
  __syncthreads();

  int C = lco[NPB];            // total packed columns this block (256 for alternating widths)
  int base = gstart[g];

  // Phase 1: one packed column per thread; all 4 waves issue coalesced dword loads.
  for (int c = tid; c < C; c += TPB) {
    long long t = (long long)base + c;
    if (t > (long long)TOT - 1) t = TOT - 1;   // ref clamp (only masked positions)
    const float* p = W2 + t;
    double acc[BATCH];
#pragma unroll
    for (int b = 0; b < BATCH; ++b) acc[b] = 0.0;
#pragma unroll 15
    for (int k = 0; k < DHID; ++k) {
      double w = (double)p[(size_t)k * TOT];
#pragma unroll
      for (int b = 0; b < BATCH; ++b) acc[b] += sh_hid[k * BATCH + b] * w;
    }
    double bb = (double)b2[t];
#pragma unroll
    for (int b = 0; b < BATCH; ++b)
      lg[b][c] = 2.5 * tanh((acc[b] + bb) / 5.0);
  }
  __syncthreads();

  // Phase 2: per (b, node): softmax probs + gumbel-argmax action
  if (tid < BATCH * NPB) {
    int b = tid >> 5;
    int i = tid & 31;
    int node = n0 + i;
    int width = nw[i];
    int off = lco[i];

    double m = -1.0e300;
    for (int j = 0; j < width; ++j) m = fmax(m, lg[b][off + j]);
    double s = 0.0;
    int pb = i * 12;
    for (int j = 0; j < width; ++j) {
      double e = exp(lg[b][off + j] - m);
      s += e;
      pbuf[b][pb + j] = (float)e;
    }
    for (int j = width; j < 12; ++j) pbuf[b][pb + j] = 0.0f;
    float inv = (float)(1.0 / s);
    for (int j = 0; j < width; ++j) pbuf[b][pb + j] *= inv;

    // action = argmax_j (g_j + gumbel(flat_idx)); masked j are finfo.min -> never win
    uint32_t fb = (uint32_t)(b * NNODES + node) * 12u;
    double best = -1.0e300; int bi = 0;
    for (int j = 0; j < width; ++j) {
      double val = lg[b][off + j] + gumbel_at(fb + (uint32_t)j);
      if (val > best) { best = val; bi = j; }
    }
    out[(size_t)PROBS_ELEMS + (size_t)b * NNODES + node] = (float)bi;
  }
  __syncthreads();

  // Phase 3: coalesced probs copy-out (per b: 384 contiguous floats = 96 float4)
#pragma unroll
  for (int b = 0; b < BATCH; ++b) {
    float4* dst = reinterpret_cast<float4*>(out + ((size_t)b * NNODES + n0) * 12);
    const float4* src = reinterpret_cast<const float4*>(&pbuf[b][0]);
    for (int q = tid; q < NPB * 12 / 4; q += TPB) dst[q] = src[q];
  }
}

extern "C" void kernel_launch(void* const* d_in, const int* in_sizes, int n_in,
                              void* d_out, int out_size, void* d_ws, size_t ws_size,
                              hipStream_t stream) {
  const float* x   = (const float*)d_in[0];
  const float* W1  = (const float*)d_in[1];
  const float* b1  = (const float*)d_in[2];
  const float* W2  = (const float*)d_in[3];
  const float* b2  = (const float*)d_in[4];
  const int*   nis = (const int*)d_in[5];
  float* out = (float*)d_out;

  char* ws = (char*)d_ws;
  double* hid   = (double*)ws;              // 2400 B
  int*    gs    = (int*)(ws + 4096);        // 6400 * 4 = 25600 B
  int*    gst   = (int*)(ws + 32768);       // 6400 * 4 = 25600 B

  hipLaunchKernelGGL(kA, dim3(NNODES / 1024), dim3(256), 0, stream, nis, gs);
  hipLaunchKernelGGL(kB, dim3(1), dim3(1024), 0, stream, gs, gst, x, W1, b1, hid);
  hipLaunchKernelGGL(kC, dim3(NBLK), dim3(TPB), 0, stream, W2, b2, nis, hid, gst, out);
}